// Round 10
// baseline (139.309 us; speedup 1.0000x reference)
//
#include <hip/hip_runtime.h>
#include <cmath>

#define B_  16
#define S_  512
#define DI  64
#define DS  64
#define RR  4
#define CH  8
#define CL  64
#define CLIPM 1.0e6f
#define NBLK 256

typedef float f32x4 __attribute__((ext_vector_type(4)));

// ws layout (floats):
#define WS_U    524288        // u     [B*S][DI]
#define WS_BM   1048576       // bm    [B*S][DS]
#define WS_CML  1572864       // cml   [B][DS]
#define WS_SUM  1573888       // f32x4 sums [B][CH][DI][DS]  (8 MB)
#define WS_BAR  3671040       // 4 u32 barrier words
#define WS_NEED_BYTES ((size_t)(WS_BAR + 4) * sizeof(float))

__device__ __forceinline__ float clampM(float v) {
    return fminf(fmaxf(v, -CLIPM), CLIPM);
}

__device__ __forceinline__ float dot64(const float* __restrict__ row,
                                       const float* xsv) {
    float a = 0.f;
    #pragma unroll
    for (int i = 0; i < 16; ++i) {
        const f32x4 w  = *reinterpret_cast<const f32x4*>(row + 4 * i);
        const f32x4 xv = *reinterpret_cast<const f32x4*>(xsv + 4 * i);
        a += w.x * xv.x + w.y * xv.y + w.z * xv.z + w.w * xv.w;
    }
    return a;
}

// Generation-counter grid barrier, device (agent) scope. Barrier words are
// zeroed by hipMemsetAsync at the start of every kernel_launch, so each
// launch starts from a known state. All 256 blocks are co-resident
// (1 block/CU at <=256 VGPR, grid == CU count), so spinning is safe.
__device__ __forceinline__ void grid_barrier(unsigned* bar, int which) {
    __syncthreads();
    if (threadIdx.x == 0) {
        unsigned* cnt = bar + 2 * which;
        unsigned* gen = bar + 2 * which + 1;
        __threadfence();
        const unsigned g = __hip_atomic_load(gen, __ATOMIC_RELAXED, __HIP_MEMORY_SCOPE_AGENT);
        const unsigned a = __hip_atomic_fetch_add(cnt, 1u, __ATOMIC_ACQ_REL, __HIP_MEMORY_SCOPE_AGENT);
        if (a == NBLK - 1u) {
            __hip_atomic_store(cnt, 0u, __ATOMIC_RELAXED, __HIP_MEMORY_SCOPE_AGENT);
            __hip_atomic_store(gen, g + 1u, __ATOMIC_RELEASE, __HIP_MEMORY_SCOPE_AGENT);
        } else {
            while (__hip_atomic_load(gen, __ATOMIC_ACQUIRE, __HIP_MEMORY_SCOPE_AGENT) == g)
                __builtin_amdgcn_s_sleep(8);
        }
        __threadfence();
    }
    __syncthreads();
}

// ONE kernel, three phases, two internal grid barriers, zero launch gaps.
__global__ __launch_bounds__(512, 1)
void ssm_fused(const float* __restrict__ x, const float* __restrict__ Wx,
               const float* __restrict__ bx, const float* __restrict__ Wdt,
               const float* __restrict__ bdt, const float* __restrict__ A_log,
               const float* __restrict__ Dp, float* __restrict__ ws,
               float* __restrict__ out, unsigned* __restrict__ bar)
{
    const int tid  = threadIdx.x;
    const int bid  = blockIdx.x;      // 0..255
    const int lane = tid & 63;
    const int wv   = tid >> 6;        // 0..7

    __shared__ float xs_s[8][4][DI];

    // ---------------- phase 0: projections (wave = 4 timesteps) ----------
    {
        const int wgid = bid * 8 + wv;            // 0..2047; bt = wgid*4+i
        #pragma unroll
        for (int i = 0; i < 4; ++i)
            xs_s[wv][i][lane] = x[(size_t)(wgid * 4 + i) * DI + lane];
    }
    __syncthreads();
    {
        const int wgid = bid * 8 + wv;
        const float a_l = -expf(A_log[lane]);     // rows of A_log identical
        float qv = a_l * a_l;
        #pragma unroll
        for (int off = 32; off > 0; off >>= 1) qv += __shfl_xor(qv, off);

        f32x4 wxr[16];
        {
            const float* wr = Wx + lane * DI;
            #pragma unroll
            for (int i = 0; i < 16; ++i)
                wxr[i] = *reinterpret_cast<const f32x4*>(wr + 4 * i);
        }
        const float bxl  = bx[lane];
        const f32x4 wdt4 = *reinterpret_cast<const f32x4*>(Wdt + lane * RR);
        const float bdtl = bdt[lane];

        float dtr = 0.f;                           // lanes 0..15: (i=lane>>2, j=lane&3)
        if (lane < 16) {
            const int i = lane >> 2, j = lane & 3;
            dtr = bx[DS + j] + dot64(Wx + (DS + j) * DI, &xs_s[wv][i][0]);
        }

        #pragma unroll
        for (int i = 0; i < 4; ++i) {
            const int bt = wgid * 4 + i;
            float accB = bxl;
            #pragma unroll
            for (int q = 0; q < 16; ++q) {
                const f32x4 xv = *reinterpret_cast<const f32x4*>(&xs_s[wv][i][4 * q]);
                accB += wxr[q].x * xv.x + wxr[q].y * xv.y + wxr[q].z * xv.z + wxr[q].w * xv.w;
            }
            float dtv = bdtl;
            dtv += __shfl(dtr, i * 4 + 0) * wdt4.x;
            dtv += __shfl(dtr, i * 4 + 1) * wdt4.y;
            dtv += __shfl(dtr, i * 4 + 2) * wdt4.z;
            dtv += __shfl(dtr, i * 4 + 3) * wdt4.w;

            float sv = a_l * dtv;
            #pragma unroll
            for (int off = 32; off > 0; off >>= 1) sv += __shfl_xor(sv, off);

            const float E   = expm1f(sv);
            const float phi = (fabsf(sv) < 1e-3f)
                                ? fmaf(sv, fmaf(sv, 1.0f / 6.0f, 0.5f), 1.0f)
                                : (E / sv);
            ws[(size_t)bt * DI + lane]          = phi * dtv;
            ws[WS_U  + (size_t)bt * DI + lane]  = xs_s[wv][i][lane] * (E / qv) * a_l;
            ws[WS_BM + (size_t)bt * DI + lane]  = accB;

            if ((bt & (S_ - 1)) == S_ - 1) {      // t == 511 of its b
                const float accC = bx[DS + RR + lane]
                                 + dot64(Wx + (DS + RR + lane) * DI, &xs_s[wv][i][0]);
                ws[WS_CML + (bt >> 9) * DS + lane] = accC;
            }
        }
    }

    grid_barrier(bar, 0);

    // ---------------- phase A: exact chunk summaries ----------------------
    // block = (b, c, d-half); thread = (dl, n-group of 4); 4 chains/thread
    const int b  = bid >> 4;
    const int c  = (bid >> 1) & 7;
    const int dh = bid & 1;
    const int dl = tid >> 4;          // 0..31
    const int d  = dh * 32 + dl;
    const int n0 = (tid & 15) << 2;

    const f32x4 alog4 = *reinterpret_cast<const f32x4*>(A_log + n0);
    const float an[4] = { -expf(alog4.x), -expf(alog4.y), -expf(alog4.z), -expf(alog4.w) };
    float dlt[4];
    #pragma unroll
    for (int k = 0; k < 4; ++k) dlt[k] = (d == n0 + k) ? 1.f : 0.f;

    const float* phidt = ws + (size_t)(b * S_) * DI + d;
    const float* uws   = ws + WS_U  + (size_t)(b * S_) * DI + d;
    const float* bmp   = ws + WS_BM + (size_t)(b * S_) * DI + n0;

    {
        float al[4], be[4], lo[4], hi[4];
        #pragma unroll
        for (int k = 0; k < 4; ++k) { al[k] = 1.f; be[k] = 0.f; lo[k] = -CLIPM; hi[k] = CLIPM; }

        const int t0 = c * CL;
        #pragma unroll 4
        for (int j = 0; j < CL; ++j) {
            const int t = t0 + j;
            const float pv = phidt[(size_t)t * DI];
            const float uv = uws[(size_t)t * DI];
            const f32x4 bv = *reinterpret_cast<const f32x4*>(bmp + (size_t)t * DI);
            const float bva[4] = { bv.x, bv.y, bv.z, bv.w };
            #pragma unroll
            for (int k = 0; k < 4; ++k) {
                const float av = fmaf(pv, an[k], dlt[k]);
                const float w  = uv * bva[k];
                al[k] = al[k] * av;
                be[k] = fmaf(av, be[k], w);
                const float u1 = fmaf(av, lo[k], w);
                const float u2 = fmaf(av, hi[k], w);
                lo[k] = clampM(fminf(u1, u2));
                hi[k] = clampM(fmaxf(u1, u2));
            }
        }
        f32x4* sum = reinterpret_cast<f32x4*>(ws + WS_SUM);
        const size_t sb = (((size_t)b * CH + c) * DI + d) * DS + n0;
        #pragma unroll
        for (int k = 0; k < 4; ++k) {
            f32x4 s = { al[k], be[k], lo[k], hi[k] };
            sum[sb + k] = s;
        }
    }

    grid_barrier(bar, 1);

    // ---------------- phase B: compose h_in in registers ------------------
    float h[4] = { 0.f, 0.f, 0.f, 0.f };
    {
        const f32x4* sum = reinterpret_cast<const f32x4*>(ws + WS_SUM);
        for (int c2 = 0; c2 < c; ++c2) {
            const size_t sb = (((size_t)b * CH + c2) * DI + d) * DS + n0;
            #pragma unroll
            for (int k = 0; k < 4; ++k) {
                const f32x4 s = sum[sb + k];
                h[k] = fminf(fmaxf(fmaf(s.x, h[k], s.y), s.z), s.w);
            }
        }
    }

    // ---------------- phase C: replay + stream h out ----------------------
    {
        const int t0 = c * CL;
        #pragma unroll 2
        for (int j = 0; j < CL; ++j) {
            const int t = t0 + j;
            const float pv = phidt[(size_t)t * DI];
            const float uv = uws[(size_t)t * DI];
            const f32x4 bv = *reinterpret_cast<const f32x4*>(bmp + (size_t)t * DI);
            const float bva[4] = { bv.x, bv.y, bv.z, bv.w };
            #pragma unroll
            for (int k = 0; k < 4; ++k) {
                const float av = fmaf(pv, an[k], dlt[k]);
                h[k] = clampM(fmaf(av, h[k], uv * bva[k]));
            }
            f32x4 hv = { h[0], h[1], h[2], h[3] };
            *reinterpret_cast<f32x4*>(
                out + 1024 + (((size_t)(b * S_ + t)) * DI + d) * DS + n0) = hv;
        }

        if (c == CH - 1) {
            const f32x4 cm = *reinterpret_cast<const f32x4*>(ws + WS_CML + b * DS + n0);
            float v = h[0] * cm.x + h[1] * cm.y + h[2] * cm.z + h[3] * cm.w;
            v += __shfl_xor(v, 1);
            v += __shfl_xor(v, 2);
            v += __shfl_xor(v, 4);
            v += __shfl_xor(v, 8);
            if ((tid & 15) == 0)
                out[b * DI + d] = v + Dp[d] * x[((size_t)(b * S_) + S_ - 1) * DI + d];
        }
    }
}

// ---------------- fallback (R8-proven 2-kernel path) ----------------------
__global__ __launch_bounds__(64)
void ssm_k1f(const float* __restrict__ x, const float* __restrict__ Wx,
             const float* __restrict__ bx, const float* __restrict__ Wdt,
             const float* __restrict__ bdt, const float* __restrict__ A_log,
             float* __restrict__ ws)
{
    __shared__ float xs[DI];
    __shared__ float dtr_s[RR];
    const int bt   = blockIdx.x;
    const int lane = threadIdx.x;

    const float xv = x[bt * DI + lane];
    xs[lane] = xv;
    const float a_l = -expf(A_log[lane]);
    __syncthreads();

    float accB = bx[lane] + dot64(Wx + lane * DI, xs);
    if (lane < RR)
        dtr_s[lane] = bx[DS + lane] + dot64(Wx + (DS + lane) * DI, xs);
    __syncthreads();

    float dtv = bdt[lane];
    #pragma unroll
    for (int r = 0; r < RR; ++r) dtv += dtr_s[r] * Wdt[lane * RR + r];

    float sv = a_l * dtv;
    float qv = a_l * a_l;
    #pragma unroll
    for (int off = 32; off > 0; off >>= 1) {
        sv += __shfl_xor(sv, off);
        qv += __shfl_xor(qv, off);
    }
    const float E   = expm1f(sv);
    const float phi = (fabsf(sv) < 1e-3f)
                        ? fmaf(sv, fmaf(sv, 1.0f / 6.0f, 0.5f), 1.0f)
                        : (E / sv);

    ws[bt * DI + lane]          = phi * dtv;
    ws[WS_U + bt * DI + lane]   = xv * (E / qv) * a_l;
    ws[WS_BM + bt * DI + lane]  = accB;
    if ((bt & (S_ - 1)) == (S_ - 1))
        ws[WS_CML + (bt >> 9) * DS + lane] = bx[DS + RR + lane] + dot64(Wx + (DS + RR + lane) * DI, xs);
}

__global__ __launch_bounds__(256)
void ssm_k2f(const float* __restrict__ ws, const float* __restrict__ x,
             const float* __restrict__ A_log, const float* __restrict__ Dp,
             float* __restrict__ out)
{
    const int tid  = threadIdx.x;
    const int n    = tid & 63;
    const int dsub = tid >> 6;
    const int b    = blockIdx.x >> 4;
    const int dg   = blockIdx.x & 15;
    const int d    = dg * 4 + dsub;

    const float a_n   = -expf(A_log[n]);
    const float delta = (d == n) ? 1.0f : 0.0f;

    const float* phidt = ws + (size_t)(b * S_) * DI + d;
    const float* uws   = ws + WS_U + (size_t)(b * S_) * DI + d;
    const float* bmws  = ws + WS_BM + (size_t)(b * S_) * DI + n;
    float* po = out + 1024 + (size_t)(b * S_) * (DI * DS) + d * DS + n;

    float h = 0.0f;
    #pragma unroll 16
    for (int t = 0; t < S_; ++t) {
        const float av = fmaf(phidt[(size_t)t * DI], a_n, delta);
        h = fmaf(av, h, uws[(size_t)t * DI] * bmws[(size_t)t * DI]);
        h = clampM(h);
        po[(size_t)t * (DI * DS)] = h;
    }
    float v = h * ws[WS_CML + b * DS + n];
    #pragma unroll
    for (int off = 32; off > 0; off >>= 1) v += __shfl_xor(v, off);
    if (n == 0)
        out[b * DI + d] = v + Dp[d] * x[((b * S_) + S_ - 1) * DI + d];
}

extern "C" void kernel_launch(void* const* d_in, const int* in_sizes, int n_in,
                              void* d_out, int out_size, void* d_ws, size_t ws_size,
                              hipStream_t stream)
{
    const float* x     = (const float*)d_in[0];
    const float* Wx    = (const float*)d_in[1];
    const float* bx    = (const float*)d_in[2];
    const float* Wdt   = (const float*)d_in[3];
    const float* bdt   = (const float*)d_in[4];
    const float* A_log = (const float*)d_in[5];
    const float* Dp    = (const float*)d_in[6];
    float* out = (float*)d_out;
    float* ws  = (float*)d_ws;

    if (ws_size >= WS_NEED_BYTES) {
        unsigned* bar = reinterpret_cast<unsigned*>(ws + WS_BAR);
        hipMemsetAsync(bar, 0, 4 * sizeof(unsigned), stream);
        ssm_fused<<<NBLK, 512, 0, stream>>>(x, Wx, bx, Wdt, bdt, A_log, Dp, ws, out, bar);
    } else {
        ssm_k1f<<<B_ * S_, 64, 0, stream>>>(x, Wx, bx, Wdt, bdt, A_log, ws);
        ssm_k2f<<<B_ * 16, 256, 0, stream>>>(ws, x, A_log, Dp, out);
    }
}

// Round 11
// 70.735 us; speedup vs baseline: 1.9694x; 1.9694x over previous
//
#include <hip/hip_runtime.h>
#include <cmath>

#define B_  16
#define S_  512
#define DI  64
#define DS  64
#define RR  4
#define CH  8
#define CL  64
#define CLIPM 1.0e6f

typedef float f32x4 __attribute__((ext_vector_type(4)));

// ws layout (floats):
#define WS_U    524288        // u     [B*S][DI]
#define WS_BM   1048576       // bm    [B*S][DS]
#define WS_CML  1572864       // cml   [B][DS]
#define WS_SUM  1573888       // f32x4 sums [B][CH][DI][DS]  (8 MB)
// total 3,671,040 floats = 14.7 MB  (fits: R10's ws_size check passed)

__device__ __forceinline__ float clampM(float v) {
    return fminf(fmaxf(v, -CLIPM), CLIPM);
}

__device__ __forceinline__ float dot64(const float* __restrict__ row,
                                       const float* xsv) {
    float a = 0.f;
    #pragma unroll
    for (int i = 0; i < 16; ++i) {
        const f32x4 w  = *reinterpret_cast<const f32x4*>(row + 4 * i);
        const f32x4 xv = *reinterpret_cast<const f32x4*>(xsv + 4 * i);
        a += w.x * xv.x + w.y * xv.y + w.z * xv.z + w.w * xv.w;
    }
    return a;
}

// k1: 8 timesteps per block; Wx row `lane` held in VGPRs, reused 8x. (R9-proven)
__global__ __launch_bounds__(64)
void ssm_k1(const float* __restrict__ x, const float* __restrict__ Wx,
            const float* __restrict__ bx, const float* __restrict__ Wdt,
            const float* __restrict__ bdt, const float* __restrict__ A_log,
            float* __restrict__ ws)
{
    __shared__ float xs[8][DI];
    __shared__ float dtr_s[8][RR];
    const int bt0  = blockIdx.x * 8;
    const int lane = threadIdx.x;

    #pragma unroll
    for (int r = 0; r < 8; ++r)
        xs[r][lane] = x[(size_t)(bt0 + r) * DI + lane];
    const float a_l = -expf(A_log[lane]);   // rows of A_log identical
    const float bxl = bx[lane];
    __syncthreads();

    f32x4 wxr[16];
    {
        const float* wr = Wx + lane * DI;
        #pragma unroll
        for (int i = 0; i < 16; ++i)
            wxr[i] = *reinterpret_cast<const f32x4*>(wr + 4 * i);
    }

    float accB[8];
    #pragma unroll
    for (int r = 0; r < 8; ++r) {
        float a = bxl;
        #pragma unroll
        for (int i = 0; i < 16; ++i) {
            const f32x4 xv4 = *reinterpret_cast<const f32x4*>(&xs[r][4 * i]);
            a += wxr[i].x * xv4.x + wxr[i].y * xv4.y + wxr[i].z * xv4.z + wxr[i].w * xv4.w;
        }
        accB[r] = a;
    }

    if (lane < 32) {
        const int j = lane & 3, r = lane >> 2;
        dtr_s[r][j] = bx[DS + j] + dot64(Wx + (DS + j) * DI, &xs[r][0]);
    }
    __syncthreads();

    float qv = a_l * a_l;
    #pragma unroll
    for (int off = 32; off > 0; off >>= 1) qv += __shfl_xor(qv, off);

    const f32x4 wdt4 = *reinterpret_cast<const f32x4*>(Wdt + lane * RR);
    const float bdtl = bdt[lane];

    #pragma unroll
    for (int r = 0; r < 8; ++r) {
        float dtv = bdtl + dtr_s[r][0] * wdt4.x + dtr_s[r][1] * wdt4.y
                         + dtr_s[r][2] * wdt4.z + dtr_s[r][3] * wdt4.w;
        float sv = a_l * dtv;
        #pragma unroll
        for (int off = 32; off > 0; off >>= 1) sv += __shfl_xor(sv, off);

        const float E   = expm1f(sv);
        const float phi = (fabsf(sv) < 1e-3f)
                            ? fmaf(sv, fmaf(sv, 1.0f / 6.0f, 0.5f), 1.0f)
                            : (E / sv);
        const int bt = bt0 + r;
        ws[(size_t)bt * DI + lane]         = phi * dtv;
        ws[WS_U + (size_t)bt * DI + lane]  = xs[r][lane] * (E / qv) * a_l;
        ws[WS_BM + (size_t)bt * DI + lane] = accB[r];
    }

    if ((bt0 & (S_ - 1)) == S_ - 8) {
        ws[WS_CML + (bt0 >> 9) * DS + lane] =
            bx[DS + RR + lane] + dot64(Wx + (DS + RR + lane) * DI, &xs[7][0]);
    }
}

// kA: exact chunk summary h -> clamp(alpha*h+beta, lo, hi); ONE chain/thread,
// 2048 blocks (full occupancy), no stores in the loop. Sums -> ws.
__global__ __launch_bounds__(256)
void ssm_kA(float* __restrict__ ws, const float* __restrict__ A_log)
{
    const int tid = threadIdx.x;
    const int dq  = blockIdx.x & 15;
    const int c   = (blockIdx.x >> 4) & 7;
    const int b   = blockIdx.x >> 7;
    const int d   = dq * 4 + (tid >> 6);
    const int n   = tid & 63;

    const float a_n   = -expf(A_log[n]);
    const float delta = (d == n) ? 1.0f : 0.0f;

    const float* phidt = ws + (size_t)(b * S_) * DI + d;
    const float* uws   = ws + WS_U  + (size_t)(b * S_) * DI + d;
    const float* bmp   = ws + WS_BM + (size_t)(b * S_) * DI + n;

    float al = 1.f, be = 0.f, lo = -CLIPM, hi = CLIPM;
    const int t0 = c * CL;
    #pragma unroll 8
    for (int j = 0; j < CL; ++j) {
        const int t = t0 + j;
        const float av = fmaf(phidt[(size_t)t * DI], a_n, delta);
        const float w  = uws[(size_t)t * DI] * bmp[(size_t)t * DI];
        al = al * av;
        be = fmaf(av, be, w);
        const float u1 = fmaf(av, lo, w);
        const float u2 = fmaf(av, hi, w);
        lo = clampM(fminf(u1, u2));
        hi = clampM(fmaxf(u1, u2));
    }

    f32x4* sum = reinterpret_cast<f32x4*>(ws + WS_SUM);
    f32x4 s = { al, be, lo, hi };
    sum[(((size_t)b * CH + c) * DI + d) * DS + n] = s;
}

// kC: compose prologue (exact h_in from sums in ws) + replay; 4 chains/thread,
// f32x4 stores -> 1KB contiguous per wave. (R6-proven mapping)
__global__ __launch_bounds__(256)
void ssm_kC(const float* __restrict__ ws, const float* __restrict__ x,
            const float* __restrict__ A_log, const float* __restrict__ Dp,
            float* __restrict__ out)
{
    const int tid = threadIdx.x;
    const int dg  = blockIdx.x & 3;
    const int c   = (blockIdx.x >> 2) & 7;
    const int b   = blockIdx.x >> 5;
    const int dl  = tid >> 4;
    const int n0  = (tid & 15) << 2;
    const int d   = dg * 16 + dl;

    const f32x4 alog4 = *reinterpret_cast<const f32x4*>(A_log + n0);
    const float an[4] = { -expf(alog4.x), -expf(alog4.y), -expf(alog4.z), -expf(alog4.w) };
    float dlt[4];
    #pragma unroll
    for (int k = 0; k < 4; ++k) dlt[k] = (d == n0 + k) ? 1.f : 0.f;

    // compose h_in from the c preceding chunk summaries (exact)
    float h[4] = { 0.f, 0.f, 0.f, 0.f };
    {
        const f32x4* sum = reinterpret_cast<const f32x4*>(ws + WS_SUM);
        for (int c2 = 0; c2 < c; ++c2) {
            const size_t sb = (((size_t)b * CH + c2) * DI + d) * DS + n0;
            #pragma unroll
            for (int k = 0; k < 4; ++k) {
                const f32x4 s = sum[sb + k];
                h[k] = fminf(fmaxf(fmaf(s.x, h[k], s.y), s.z), s.w);
            }
        }
    }

    const float* phidt = ws + (size_t)(b * S_) * DI + d;
    const float* uws   = ws + WS_U  + (size_t)(b * S_) * DI + d;
    const float* bmp   = ws + WS_BM + (size_t)(b * S_) * DI + n0;

    const int t0 = c * CL;
    #pragma unroll 4
    for (int j = 0; j < CL; ++j) {
        const int t = t0 + j;
        const float pv = phidt[(size_t)t * DI];
        const float uv = uws[(size_t)t * DI];
        const f32x4 bv = *reinterpret_cast<const f32x4*>(bmp + (size_t)t * DI);
        const float bva[4] = { bv.x, bv.y, bv.z, bv.w };
        #pragma unroll
        for (int k = 0; k < 4; ++k) {
            const float av = fmaf(pv, an[k], dlt[k]);
            h[k] = clampM(fmaf(av, h[k], uv * bva[k]));
        }
        f32x4 hv = { h[0], h[1], h[2], h[3] };
        *reinterpret_cast<f32x4*>(
            out + 1024 + (((size_t)(b * S_ + t)) * DI + d) * DS + n0) = hv;
    }

    if (c == CH - 1) {
        const f32x4 cm = *reinterpret_cast<const f32x4*>(ws + WS_CML + b * DS + n0);
        float v = h[0] * cm.x + h[1] * cm.y + h[2] * cm.z + h[3] * cm.w;
        v += __shfl_xor(v, 1);
        v += __shfl_xor(v, 2);
        v += __shfl_xor(v, 4);
        v += __shfl_xor(v, 8);
        if ((tid & 15) == 0)
            out[b * DI + d] = v + Dp[d] * x[((size_t)(b * S_) + S_ - 1) * DI + d];
    }
}

extern "C" void kernel_launch(void* const* d_in, const int* in_sizes, int n_in,
                              void* d_out, int out_size, void* d_ws, size_t ws_size,
                              hipStream_t stream)
{
    const float* x     = (const float*)d_in[0];
    const float* Wx    = (const float*)d_in[1];
    const float* bx    = (const float*)d_in[2];
    const float* Wdt   = (const float*)d_in[3];
    const float* bdt   = (const float*)d_in[4];
    const float* A_log = (const float*)d_in[5];
    const float* Dp    = (const float*)d_in[6];
    float* out = (float*)d_out;
    float* ws  = (float*)d_ws;

    ssm_k1<<<B_ * S_ / 8, 64, 0, stream>>>(x, Wx, bx, Wdt, bdt, A_log, ws);
    ssm_kA<<<B_ * CH * 16, 256, 0, stream>>>(ws, A_log);
    ssm_kC<<<B_ * CH * 4, 256, 0, stream>>>(ws, x, A_log, Dp, out);
}

// Round 12
// 68.119 us; speedup vs baseline: 2.0451x; 1.0384x over previous
//
#include <hip/hip_runtime.h>
#include <cmath>

#define B_  16
#define S_  512
#define DI  64
#define DS  64
#define RR  4
#define CH  8
#define CL  64
#define CLIPM 1.0e6f

typedef float f32x4 __attribute__((ext_vector_type(4)));

// ws layout (floats):
#define WS_U    524288        // u     [B*S][DI]
#define WS_BM   1048576       // bm    [B*S][DS]
#define WS_CML  1572864       // cml   [B][DS]
#define WS_SUM  1573888       // f32x4 sums [B][CH][DI][DS]  (8 MB)
// total 3,671,040 floats = 14.7 MB (R10/R11 confirmed ws_size fits)

__device__ __forceinline__ float clampM(float v) {
    return fminf(fmaxf(v, -CLIPM), CLIPM);
}

__device__ __forceinline__ float dot64(const float* __restrict__ row,
                                       const float* xsv) {
    float a = 0.f;
    #pragma unroll
    for (int i = 0; i < 16; ++i) {
        const f32x4 w  = *reinterpret_cast<const f32x4*>(row + 4 * i);
        const f32x4 xv = *reinterpret_cast<const f32x4*>(xsv + 4 * i);
        a += w.x * xv.x + w.y * xv.y + w.z * xv.z + w.w * xv.w;
    }
    return a;
}

// k1: 8 timesteps per block; Wx row in VGPRs, reused 8x. (R9/R11-proven)
__global__ __launch_bounds__(64)
void ssm_k1(const float* __restrict__ x, const float* __restrict__ Wx,
            const float* __restrict__ bx, const float* __restrict__ Wdt,
            const float* __restrict__ bdt, const float* __restrict__ A_log,
            float* __restrict__ ws)
{
    __shared__ float xs[8][DI];
    __shared__ float dtr_s[8][RR];
    const int bt0  = blockIdx.x * 8;
    const int lane = threadIdx.x;

    #pragma unroll
    for (int r = 0; r < 8; ++r)
        xs[r][lane] = x[(size_t)(bt0 + r) * DI + lane];
    const float a_l = -expf(A_log[lane]);
    const float bxl = bx[lane];
    __syncthreads();

    f32x4 wxr[16];
    {
        const float* wr = Wx + lane * DI;
        #pragma unroll
        for (int i = 0; i < 16; ++i)
            wxr[i] = *reinterpret_cast<const f32x4*>(wr + 4 * i);
    }

    float accB[8];
    #pragma unroll
    for (int r = 0; r < 8; ++r) {
        float a = bxl;
        #pragma unroll
        for (int i = 0; i < 16; ++i) {
            const f32x4 xv4 = *reinterpret_cast<const f32x4*>(&xs[r][4 * i]);
            a += wxr[i].x * xv4.x + wxr[i].y * xv4.y + wxr[i].z * xv4.z + wxr[i].w * xv4.w;
        }
        accB[r] = a;
    }

    if (lane < 32) {
        const int j = lane & 3, r = lane >> 2;
        dtr_s[r][j] = bx[DS + j] + dot64(Wx + (DS + j) * DI, &xs[r][0]);
    }
    __syncthreads();

    float qv = a_l * a_l;
    #pragma unroll
    for (int off = 32; off > 0; off >>= 1) qv += __shfl_xor(qv, off);

    const f32x4 wdt4 = *reinterpret_cast<const f32x4*>(Wdt + lane * RR);
    const float bdtl = bdt[lane];

    #pragma unroll
    for (int r = 0; r < 8; ++r) {
        float dtv = bdtl + dtr_s[r][0] * wdt4.x + dtr_s[r][1] * wdt4.y
                         + dtr_s[r][2] * wdt4.z + dtr_s[r][3] * wdt4.w;
        float sv = a_l * dtv;
        #pragma unroll
        for (int off = 32; off > 0; off >>= 1) sv += __shfl_xor(sv, off);

        const float E   = expm1f(sv);
        const float phi = (fabsf(sv) < 1e-3f)
                            ? fmaf(sv, fmaf(sv, 1.0f / 6.0f, 0.5f), 1.0f)
                            : (E / sv);
        const int bt = bt0 + r;
        ws[(size_t)bt * DI + lane]         = phi * dtv;
        ws[WS_U + (size_t)bt * DI + lane]  = xs[r][lane] * (E / qv) * a_l;
        ws[WS_BM + (size_t)bt * DI + lane] = accB[r];
    }

    if ((bt0 & (S_ - 1)) == S_ - 8) {
        ws[WS_CML + (bt0 >> 9) * DS + lane] =
            bx[DS + RR + lane] + dot64(Wx + (DS + RR + lane) * DI, &xs[7][0]);
    }
}

// kA: exact chunk summary; LDS-staged operands (wide coalesced loads once),
// inner loop = 3 LDS reads + VALU, zero per-step VMEM. 1 chain/thread.
__global__ __launch_bounds__(256)
void ssm_kA(float* __restrict__ ws, const float* __restrict__ A_log)
{
    __shared__ float pd_s[CL][4];
    __shared__ float ud_s[CL][4];
    __shared__ float bm_s[CL][DS];

    const int tid = threadIdx.x;
    const int dq  = blockIdx.x & 15;
    const int c   = (blockIdx.x >> 4) & 7;
    const int b   = blockIdx.x >> 7;
    const int d0  = dq * 4;

    const float* pg = ws + (size_t)(b * S_ + c * CL) * DI;
    const float* ug = ws + WS_U  + (size_t)(b * S_ + c * CL) * DI;
    const float* bg = ws + WS_BM + (size_t)(b * S_ + c * CL) * DI;

    // stage: pd/ud 1KB each (threads 0..127), bm 16KB (all threads, 4 rows ea)
    if (tid < CL) {
        *reinterpret_cast<f32x4*>(&pd_s[tid][0]) =
            *reinterpret_cast<const f32x4*>(pg + (size_t)tid * DI + d0);
    } else if (tid < 2 * CL) {
        const int t = tid - CL;
        *reinterpret_cast<f32x4*>(&ud_s[t][0]) =
            *reinterpret_cast<const f32x4*>(ug + (size_t)t * DI + d0);
    }
    {
        const int col = (tid & 15) * 4;
        #pragma unroll
        for (int k = 0; k < 4; ++k) {
            const int t = (tid >> 4) + 16 * k;
            *reinterpret_cast<f32x4*>(&bm_s[t][col]) =
                *reinterpret_cast<const f32x4*>(bg + (size_t)t * DI + col);
        }
    }
    __syncthreads();

    const int w = tid >> 6;        // 0..3 -> d = d0 + w
    const int n = tid & 63;
    const int d = d0 + w;

    const float a_n   = -expf(A_log[n]);
    const float delta = (d == n) ? 1.0f : 0.0f;

    float al = 1.f, be = 0.f, lo = -CLIPM, hi = CLIPM;
    #pragma unroll 8
    for (int j = 0; j < CL; ++j) {
        const float pv = pd_s[j][w];
        const float uv = ud_s[j][w];
        const float bv = bm_s[j][n];
        const float av = fmaf(pv, a_n, delta);
        const float wk = uv * bv;
        al = al * av;
        be = fmaf(av, be, wk);
        const float u1 = fmaf(av, lo, wk);
        const float u2 = fmaf(av, hi, wk);
        lo = clampM(fminf(u1, u2));
        hi = clampM(fmaxf(u1, u2));
    }

    f32x4* sum = reinterpret_cast<f32x4*>(ws + WS_SUM);
    f32x4 s = { al, be, lo, hi };
    sum[(((size_t)b * CH + c) * DI + d) * DS + n] = s;
}

// kC: compose prologue + replay; LDS-staged operands, f32x4 1KB/wave stores.
__global__ __launch_bounds__(256)
void ssm_kC(const float* __restrict__ ws, const float* __restrict__ x,
            const float* __restrict__ A_log, const float* __restrict__ Dp,
            float* __restrict__ out)
{
    __shared__ float pd_s[CL][16];
    __shared__ float ud_s[CL][16];
    __shared__ float bm_s[CL][DS];

    const int tid = threadIdx.x;
    const int dg  = blockIdx.x & 3;
    const int c   = (blockIdx.x >> 2) & 7;
    const int b   = blockIdx.x >> 5;
    const int dl  = tid >> 4;          // 0..15
    const int n0  = (tid & 15) << 2;
    const int d0  = dg * 16;
    const int d   = d0 + dl;

    const float* pg = ws + (size_t)(b * S_ + c * CL) * DI;
    const float* ug = ws + WS_U  + (size_t)(b * S_ + c * CL) * DI;
    const float* bg = ws + WS_BM + (size_t)(b * S_ + c * CL) * DI;

    // stage pd/ud 4KB each (1 f32x4/thread), bm 16KB (4 f32x4/thread)
    {
        const int t = tid >> 2, q = (tid & 3) * 4;
        *reinterpret_cast<f32x4*>(&pd_s[t][q]) =
            *reinterpret_cast<const f32x4*>(pg + (size_t)t * DI + d0 + q);
        *reinterpret_cast<f32x4*>(&ud_s[t][q]) =
            *reinterpret_cast<const f32x4*>(ug + (size_t)t * DI + d0 + q);
        const int col = (tid & 15) * 4;
        #pragma unroll
        for (int k = 0; k < 4; ++k) {
            const int tr = (tid >> 4) + 16 * k;
            *reinterpret_cast<f32x4*>(&bm_s[tr][col]) =
                *reinterpret_cast<const f32x4*>(bg + (size_t)tr * DI + col);
        }
    }

    const f32x4 alog4 = *reinterpret_cast<const f32x4*>(A_log + n0);
    const float an[4] = { -expf(alog4.x), -expf(alog4.y), -expf(alog4.z), -expf(alog4.w) };
    float dlt[4];
    #pragma unroll
    for (int k = 0; k < 4; ++k) dlt[k] = (d == n0 + k) ? 1.f : 0.f;

    // compose h_in from the c preceding chunk summaries (exact)
    float h[4] = { 0.f, 0.f, 0.f, 0.f };
    {
        const f32x4* sum = reinterpret_cast<const f32x4*>(ws + WS_SUM);
        for (int c2 = 0; c2 < c; ++c2) {
            const size_t sb = (((size_t)b * CH + c2) * DI + d) * DS + n0;
            #pragma unroll
            for (int k = 0; k < 4; ++k) {
                const f32x4 s = sum[sb + k];
                h[k] = fminf(fmaxf(fmaf(s.x, h[k], s.y), s.z), s.w);
            }
        }
    }
    __syncthreads();

    const int t0 = c * CL;
    #pragma unroll 4
    for (int j = 0; j < CL; ++j) {
        const float pv = pd_s[j][dl];
        const float uv = ud_s[j][dl];
        const f32x4 bv = *reinterpret_cast<const f32x4*>(&bm_s[j][n0]);
        const float bva[4] = { bv.x, bv.y, bv.z, bv.w };
        #pragma unroll
        for (int k = 0; k < 4; ++k) {
            const float av = fmaf(pv, an[k], dlt[k]);
            h[k] = clampM(fmaf(av, h[k], uv * bva[k]));
        }
        f32x4 hv = { h[0], h[1], h[2], h[3] };
        *reinterpret_cast<f32x4*>(
            out + 1024 + (((size_t)(b * S_ + t0 + j)) * DI + d) * DS + n0) = hv;
    }

    if (c == CH - 1) {
        const f32x4 cm = *reinterpret_cast<const f32x4*>(ws + WS_CML + b * DS + n0);
        float v = h[0] * cm.x + h[1] * cm.y + h[2] * cm.z + h[3] * cm.w;
        v += __shfl_xor(v, 1);
        v += __shfl_xor(v, 2);
        v += __shfl_xor(v, 4);
        v += __shfl_xor(v, 8);
        if ((tid & 15) == 0)
            out[b * DI + d] = v + Dp[d] * x[((size_t)(b * S_) + S_ - 1) * DI + d];
    }
}

extern "C" void kernel_launch(void* const* d_in, const int* in_sizes, int n_in,
                              void* d_out, int out_size, void* d_ws, size_t ws_size,
                              hipStream_t stream)
{
    const float* x     = (const float*)d_in[0];
    const float* Wx    = (const float*)d_in[1];
    const float* bx    = (const float*)d_in[2];
    const float* Wdt   = (const float*)d_in[3];
    const float* bdt   = (const float*)d_in[4];
    const float* A_log = (const float*)d_in[5];
    const float* Dp    = (const float*)d_in[6];
    float* out = (float*)d_out;
    float* ws  = (float*)d_ws;

    ssm_k1<<<B_ * S_ / 8, 64, 0, stream>>>(x, Wx, bx, Wdt, bdt, A_log, ws);
    ssm_kA<<<B_ * CH * 16, 256, 0, stream>>>(ws, A_log);
    ssm_kC<<<B_ * CH * 4, 256, 0, stream>>>(ws, x, A_log, Dp, out);
}